// Round 4
// baseline (366.880 us; speedup 1.0000x reference)
//
#include <hip/hip_runtime.h>
#include <cstdint>

#define BATCHES 8
#define NPTS 2048
#define NF 512
#define KNN 32
#define WAVES 8   // 512-thread block = 8 waves
#define QPW 2     // queries per wave: gather A || select B, sliced fine

// grid = 8 batches * 128 chunks = 1024 blocks; batch = blockIdx & 7 (XCD L2 affinity).
// LDS = 32768 + 4096 + 1024 = 37888 B -> 4 blocks/CU resident.
// R4: R1's proven no-spill skeleton (512 thr, 4 loads in flight per step, piece
// between issue and consume) + FULL select-B sliced into the 16 gather-A steps:
//   steps 0-3: dist x8 | 4-8: minima-sort 21 rounds | 9-10: countLE | 11-14:
//   compact x8 | 15: 16-round merge-select.
// R3 lesson: 8 loads in flight + big sort pieces => allocator gave up (64 VGPR,
// 356 MB scratch spill, 219us). Spill check: WRITE_SIZE must be exactly 32768 KB.

typedef float vfloat4 __attribute__((ext_vector_type(4)));  // native vec for nt-store

__global__ __launch_bounds__(512, 4)
void pointnetpp_knn_maxpool(const float* __restrict__ x,
                            const float* __restrict__ points,
                            float* __restrict__ out) {
    __shared__ __align__(16) float    pts4[NPTS * 4];    // [N][4]: one b128/candidate
    __shared__ __align__(16) uint64_t ckey[WAVES][64];   // candidate keys (fast path)
    __shared__ __align__(16) int      sel[WAVES][KNN];   // tie-fallback emit only

    const int tid  = threadIdx.x;
    const int lane = tid & 63;
    const int w    = tid >> 6;

    const int b     = blockIdx.x & 7;
    const int chunk = blockIdx.x >> 3;

    // ---- stage points[b] into LDS as [N][4] (pad .w) ----
    {
        const float* src = points + (size_t)b * NPTS * 3;
        for (int p = tid; p < NPTS; p += 512) {
            float4* d = (float4*)&pts4[p * 4];
            *d = make_float4(src[p * 3 + 0], src[p * 3 + 1], src[p * 3 + 2], 0.f);
        }
    }
    __syncthreads();

    const uint64_t lmlt = (1ull << lane) - 1ull;
    const float*   xb   = x + (size_t)b * NPTS * NF;

    const int iA = (chunk * WAVES + w) * QPW;   // this wave's queries: iA, iA+1

    uint32_t db[32];   // shared across A and B (register-resident)

    auto countLE = [&](uint32_t t) -> uint32_t {
        uint32_t c = 0;
        #pragma unroll
        for (int j = 0; j < 32; ++j)
            c += (uint32_t)__builtin_popcountll(__ballot(db[j] <= t));
        return c;
    };

    auto distTo = [&](int qi) {
        const float4 qp = *(const float4*)&pts4[qi * 4];
        #pragma unroll
        for (int j = 0; j < 32; ++j) {
            const int n = lane + (j << 6);
            const float4 pp = *(const float4*)&pts4[n * 4];
            const float dx = qp.x - pp.x;
            const float dy = qp.y - pp.y;
            const float dz = qp.z - pp.z;
            db[j] = __float_as_uint(dx * dx + dy * dy + dz * dz);
        }
    };

    // compact <=64 candidates (d2<=thr) to LDS keys, then TOP-32 MERGE-SELECT
    // (15 bitonic rounds k=2..32 + 1 min-merge; maxpool is order-invariant,
    // set matches ref tie order via (d2,idx) keys). Requires 32<=cthr<=64.
    auto compactSelect = [&](uint32_t thr, uint32_t cthr) -> int {
        uint32_t base = 0;
        #pragma unroll
        for (int j = 0; j < 32; ++j) {
            const bool     p = db[j] <= thr;
            const uint64_t m = __ballot(p);
            if (p) {
                const int slot = (int)base + (int)__popcll(m & lmlt);
                ckey[w][slot] = (((uint64_t)db[j]) << 11) | (uint64_t)(lane + (j << 6));
            }
            base += (uint32_t)__builtin_popcountll(m);
        }
        uint64_t key = (lane < (int)cthr) ? ckey[w][lane] : ~0ull;
        #pragma unroll
        for (int k = 2; k <= 32; k <<= 1) {
            #pragma unroll
            for (int j = k >> 1; j > 0; j >>= 1) {
                const uint64_t other = __shfl_xor((unsigned long long)key, j);
                const bool takeMin = (((lane & j) == 0) == ((lane & k) == 0));
                key = ((key < other) == takeMin) ? key : other;
            }
        }
        {
            const uint64_t other = __shfl_xor((unsigned long long)key, 32);
            const uint64_t mn = key < other ? key : other;
            const uint64_t mx = key < other ? other : key;
            key = ((lane & 32) == 0) ? mn : mx;
        }
        return (int)(key & 0x7FFull);
    };

    // exact-tie fallback: all <T, then ==T ascending index (ref tie order)
    auto tieFallback = [&](uint32_t T, int cnt_lt) -> int {
        int base_lt = 0, base_eq = 0;
        #pragma unroll
        for (int j = 0; j < 32; ++j) {
            const bool lt = db[j] < T;
            const bool eq = db[j] == T;
            const uint64_t mlt = __ballot(lt);
            const uint64_t meq = __ballot(eq);
            int slot = -1;
            if (lt)      slot = base_lt + (int)__popcll(mlt & lmlt);
            else if (eq) slot = cnt_lt + base_eq + (int)__popcll(meq & lmlt);
            if (slot >= 0 && slot < KNN) sel[w][slot] = lane + (j << 6);
            base_lt += (int)__popcll(mlt);
            base_eq += (int)__popcll(meq);
        }
        return sel[w][lane & (KNN - 1)];
    };

    // full select on current db[] (probe fast path + binary-search + tie fallback)
    auto selectFull = [&]() -> int {
        uint32_t lmin = db[0];
        #pragma unroll
        for (int j = 1; j < 32; ++j) lmin = min(lmin, db[j]);
        uint32_t sm = lmin;
        #pragma unroll
        for (int k = 2; k <= 64; k <<= 1) {
            #pragma unroll
            for (int j = k >> 1; j > 0; j >>= 1) {
                const uint32_t o  = (uint32_t)__shfl_xor((int)sm, j);
                const uint32_t mn = min(sm, o);
                const uint32_t mx = max(sm, o);
                sm = (((lane & j) == 0) == ((lane & k) == 0)) ? mn : mx;
            }
        }
        const uint32_t probe = (uint32_t)__builtin_amdgcn_readlane((int)sm, 31);
        const uint32_t hi0   = (uint32_t)__builtin_amdgcn_readlane((int)sm, 63);

        const uint32_t c1 = countLE(probe);          // >= 32 guaranteed
        if (c1 <= 64u) return compactSelect(probe, c1);
        const uint32_t cs = countLE(hi0);            // >= 64 guaranteed
        if (cs <= 64u) return compactSelect(hi0, cs);
        if (probe == 0u) return tieFallback(0u, 0);  // >=65 zero-distance dups
        uint32_t lo = 0u, hi = probe;                // c(lo)<32 (self only), c(hi)>64
        while (hi - lo > 1u) {
            const uint32_t mid = lo + ((hi - lo) >> 1);
            const uint32_t c   = countLE(mid);
            if (c >= KNN && c <= 64u) return compactSelect(mid, c);
            if (c > 64u) hi = mid; else lo = mid;
        }
        return tieFallback(hi, (int)countLE(lo));    // count(<=lo) == count(<hi)
    };

    // ================= query A: distances + select (unhidden) =================
    distTo(iA);
    const int selvA = selectFull();

    // ===== fused: gather+maxpool A (VMEM) || FULL select B sliced in 16 =====
    const float4 qpB = *(const float4*)&pts4[(iA + 1) * 4];
    float4 a0 = make_float4(-INFINITY, -INFINITY, -INFINITY, -INFINITY);
    float4 a1 = a0;

    uint32_t smB = 0, probeB = 0, cB = 0, c1B = 0, baseB = 0;
    bool     haveB = false;
    uint64_t keyB = ~0ull;

#define ISSUE(cc) \
    const int na_##cc = __builtin_amdgcn_readlane(selvA, 2*(cc))     & (NPTS - 1); \
    const int nb_##cc = __builtin_amdgcn_readlane(selvA, 2*(cc) + 1) & (NPTS - 1); \
    const float4* pa_##cc = (const float4*)(xb + (size_t)na_##cc * NF);            \
    const float4* pb_##cc = (const float4*)(xb + (size_t)nb_##cc * NF);            \
    const float4 ua0_##cc = pa_##cc[lane], ua1_##cc = pa_##cc[lane + 64];          \
    const float4 ub0_##cc = pb_##cc[lane], ub1_##cc = pb_##cc[lane + 64];

#define CONSUME(cc) \
    a0.x = fmaxf(fmaxf(a0.x, ua0_##cc.x), ub0_##cc.x); \
    a0.y = fmaxf(fmaxf(a0.y, ua0_##cc.y), ub0_##cc.y); \
    a0.z = fmaxf(fmaxf(a0.z, ua0_##cc.z), ub0_##cc.z); \
    a0.w = fmaxf(fmaxf(a0.w, ua0_##cc.w), ub0_##cc.w); \
    a1.x = fmaxf(fmaxf(a1.x, ua1_##cc.x), ub1_##cc.x); \
    a1.y = fmaxf(fmaxf(a1.y, ua1_##cc.y), ub1_##cc.y); \
    a1.z = fmaxf(fmaxf(a1.z, ua1_##cc.z), ub1_##cc.z); \
    a1.w = fmaxf(fmaxf(a1.w, ua1_##cc.w), ub1_##cc.w);

#define DIST8(h) do { \
    _Pragma("unroll") \
    for (int jj = 0; jj < 8; ++jj) { \
        const int j = (h) * 8 + jj; \
        const int n = lane + (j << 6); \
        const float4 pp = *(const float4*)&pts4[n * 4]; \
        const float dx = qpB.x - pp.x; \
        const float dy = qpB.y - pp.y; \
        const float dz = qpB.z - pp.z; \
        db[j] = __float_as_uint(dx * dx + dy * dy + dz * dz); \
    } } while (0)

#define MINMAXSTEP(k, j) do { \
    const uint32_t o_ = (uint32_t)__shfl_xor((int)smB, (j)); \
    const uint32_t mn_ = min(smB, o_), mx_ = max(smB, o_); \
    smB = (((lane & (j)) == 0) == ((lane & (k)) == 0)) ? mn_ : mx_; } while (0)

#define CLE16(h) do { \
    _Pragma("unroll") \
    for (int jj = 0; jj < 16; ++jj) { \
        const int j = (h) * 16 + jj; \
        cB += (uint32_t)__builtin_popcountll(__ballot(db[j] <= probeB)); \
    } } while (0)

#define COMPACT8(h) do { \
    _Pragma("unroll") \
    for (int jj = 0; jj < 8; ++jj) { \
        const int j = (h) * 8 + jj; \
        const bool p_ = db[j] <= probeB; \
        const uint64_t m_ = __ballot(p_); \
        if (p_ && haveB) { \
            const int slot_ = (int)baseB + (int)__popcll(m_ & lmlt); \
            ckey[w][slot_] = (((uint64_t)db[j]) << 11) | (uint64_t)(lane + (j << 6)); \
        } \
        baseB += (uint32_t)__builtin_popcountll(m_); \
    } } while (0)

#define KEYSTEP(k, j) do { \
    const uint64_t o_ = __shfl_xor((unsigned long long)keyB, (j)); \
    const bool tm_ = (((lane & (j)) == 0) == ((lane & (k)) == 0)); \
    keyB = ((keyB < o_) == tm_) ? keyB : o_; } while (0)

    // step 0..3: gather rows 0..7, dist-B
    { ISSUE(0)  DIST8(0);  CONSUME(0)  }
    { ISSUE(1)  DIST8(1);  CONSUME(1)  }
    { ISSUE(2)  DIST8(2);  CONSUME(2)  }
    { ISSUE(3)  DIST8(3);  CONSUME(3)  }
    // step 4..8: lane-min + 21-round bitonic sort of the 64 lane minima
    { ISSUE(4)
      uint32_t lm = db[0];
      #pragma unroll
      for (int j = 1; j < 32; ++j) lm = min(lm, db[j]);
      smB = lm;
      MINMAXSTEP(2, 1);
      CONSUME(4)  }
    { ISSUE(5)
      MINMAXSTEP(4, 2);  MINMAXSTEP(4, 1);
      MINMAXSTEP(8, 4);  MINMAXSTEP(8, 2);  MINMAXSTEP(8, 1);
      CONSUME(5)  }
    { ISSUE(6)
      MINMAXSTEP(16, 8); MINMAXSTEP(16, 4); MINMAXSTEP(16, 2); MINMAXSTEP(16, 1);
      MINMAXSTEP(32, 16);
      CONSUME(6)  }
    { ISSUE(7)
      MINMAXSTEP(32, 8); MINMAXSTEP(32, 4); MINMAXSTEP(32, 2); MINMAXSTEP(32, 1);
      CONSUME(7)  }
    { ISSUE(8)
      MINMAXSTEP(64, 32); MINMAXSTEP(64, 16); MINMAXSTEP(64, 8);
      MINMAXSTEP(64, 4);  MINMAXSTEP(64, 2);  MINMAXSTEP(64, 1);
      probeB = (uint32_t)__builtin_amdgcn_readlane((int)smB, 31);
      CONSUME(8)  }
    // step 9..10: countLE(probeB) in halves (probe = 32nd-smallest lane-min, c>=32)
    { ISSUE(9)   CLE16(0);  CONSUME(9)  }
    { ISSUE(10)  CLE16(1);  c1B = cB;  haveB = (c1B <= 64u);  CONSUME(10) }
    // step 11..14: compact candidates to LDS keys (predicated on haveB)
    { ISSUE(11)  COMPACT8(0);  CONSUME(11) }
    { ISSUE(12)  COMPACT8(1);  CONSUME(12) }
    { ISSUE(13)  COMPACT8(2);  CONSUME(13) }
    { ISSUE(14)  COMPACT8(3);
      keyB = (haveB && lane < (int)c1B) ? ckey[w][lane] : ~0ull;
      CONSUME(14) }
    // step 15: 15-round merge-select + min-merge (top-32 of <=64, unordered)
    { ISSUE(15)
      KEYSTEP(2, 1);
      KEYSTEP(4, 2);   KEYSTEP(4, 1);
      KEYSTEP(8, 4);   KEYSTEP(8, 2);   KEYSTEP(8, 1);
      KEYSTEP(16, 8);  KEYSTEP(16, 4);  KEYSTEP(16, 2);  KEYSTEP(16, 1);
      KEYSTEP(32, 16); KEYSTEP(32, 8);  KEYSTEP(32, 4);  KEYSTEP(32, 2); KEYSTEP(32, 1);
      {
          const uint64_t o_ = __shfl_xor((unsigned long long)keyB, 32);
          const uint64_t mn_ = keyB < o_ ? keyB : o_;
          const uint64_t mx_ = keyB < o_ ? o_ : keyB;
          keyB = ((lane & 32) == 0) ? mn_ : mx_;
      }
      CONSUME(15) }

    {
        vfloat4* orow = (vfloat4*)(out + ((size_t)b * NPTS + iA) * NF);
        __builtin_nontemporal_store(vfloat4{a0.x, a0.y, a0.z, a0.w}, &orow[lane]);
        __builtin_nontemporal_store(vfloat4{a1.x, a1.y, a1.z, a1.w}, &orow[lane + 64]);
    }

    // ================= query B: finish select (rare slow path) + gather =================
    int selvB;
    if (haveB) selvB = (int)(keyB & 0x7FFull);
    else       selvB = selectFull();   // db[] still holds B's distances

    a0 = make_float4(-INFINITY, -INFINITY, -INFINITY, -INFINITY);
    a1 = a0;
    #pragma unroll 4
    for (int jj = 0; jj < 32; jj += 2) {
        const int n0 = __builtin_amdgcn_readlane(selvB, jj)     & (NPTS - 1);
        const int n1 = __builtin_amdgcn_readlane(selvB, jj + 1) & (NPTS - 1);
        const float4* r0 = (const float4*)(xb + (size_t)n0 * NF);
        const float4* r1 = (const float4*)(xb + (size_t)n1 * NF);
        const float4 v00 = r0[lane];
        const float4 v01 = r0[lane + 64];
        const float4 v10 = r1[lane];
        const float4 v11 = r1[lane + 64];
        a0.x = fmaxf(fmaxf(a0.x, v00.x), v10.x);
        a0.y = fmaxf(fmaxf(a0.y, v00.y), v10.y);
        a0.z = fmaxf(fmaxf(a0.z, v00.z), v10.z);
        a0.w = fmaxf(fmaxf(a0.w, v00.w), v10.w);
        a1.x = fmaxf(fmaxf(a1.x, v01.x), v11.x);
        a1.y = fmaxf(fmaxf(a1.y, v01.y), v11.y);
        a1.z = fmaxf(fmaxf(a1.z, v01.z), v11.z);
        a1.w = fmaxf(fmaxf(a1.w, v01.w), v11.w);
    }
    {
        vfloat4* orow = (vfloat4*)(out + ((size_t)b * NPTS + iA + 1) * NF);
        __builtin_nontemporal_store(vfloat4{a0.x, a0.y, a0.z, a0.w}, &orow[lane]);
        __builtin_nontemporal_store(vfloat4{a1.x, a1.y, a1.z, a1.w}, &orow[lane + 64]);
    }
}

extern "C" void kernel_launch(void* const* d_in, const int* in_sizes, int n_in,
                              void* d_out, int out_size, void* d_ws, size_t ws_size,
                              hipStream_t stream) {
    const float* x      = (const float*)d_in[0];   // [8, 2048, 512] f32
    const float* points = (const float*)d_in[1];   // [8, 2048, 3]   f32
    float* out          = (float*)d_out;           // [8, 2048, 512] f32

    pointnetpp_knn_maxpool<<<dim3(BATCHES * (NPTS / (WAVES * QPW))),
                             dim3(512), 0, stream>>>(x, points, out);
}

// Round 5
// 359.998 us; speedup vs baseline: 1.0191x; 1.0191x over previous
//
#include <hip/hip_runtime.h>
#include <cstdint>

#define BATCHES 8
#define NPTS 2048
#define NF 512
#define KNN 32
#define QPB 16     // queries per block
#define NSEL 2     // producer (select) waves
#define NGAT 6     // consumer (gather) waves

// R5: producer/consumer wave specialization. R3/R4 post-mortem: ANY code reading
// all of db[32] placed between load-issue and load-consume spills catastrophically
// (allocator can't keep db AGPR-shelved while 16 load regs are live: 64 VGPR +
// 480 MB scratch traffic). So overlap select(VALU) with gather(L2) across WAVES:
//   waves 0-1: select 16 queries -> selq[][] + release flag   (R0 codegen, ~32 VGPR)
//   waves 2-7: ticket-pop queries, spin on flag, gather+maxpool (R1 loop, no spill)
// Ratio 2:6 matches measured select ~12us chip-VALU vs gather ~30us chip-L2 floor
// (1 GiB / 34.5 TB/s). grid = 8*128 = 1024 blocks = 4/CU resident (LDS ~36.3 KB),
// 32 waves/CU. batch = blockIdx & 7 keeps x[b] (4 MB) in its XCD's 4 MB L2.
// Spill tripwire: WRITE_SIZE must be exactly 32768 KB.

typedef float vfloat4 __attribute__((ext_vector_type(4)));  // native vec for nt-store

__global__ __launch_bounds__(512, 4)
void pointnetpp_knn_maxpool(const float* __restrict__ x,
                            const float* __restrict__ points,
                            float* __restrict__ out) {
    __shared__ __align__(16) float    pts4[NPTS * 4];     // [N][4]: one b128/candidate
    __shared__ __align__(16) uint64_t ckey[NSEL][64];     // select scratch (fast path)
    __shared__ __align__(16) int      tiebuf[NSEL][KNN];  // tie-fallback emit
    __shared__ __align__(16) int      selq[QPB][KNN];     // producer -> consumer
    __shared__ int flagq[QPB];                            // release flags
    __shared__ int ticket;                                // gather work counter

    const int tid  = threadIdx.x;
    const int lane = tid & 63;
    const int w    = tid >> 6;

    const int b     = blockIdx.x & 7;
    const int chunk = blockIdx.x >> 3;
    const int iBase = chunk * QPB;

    // ---- stage points[b] into LDS as [N][4] (pad .w); init flags/ticket ----
    {
        const float* src = points + (size_t)b * NPTS * 3;
        for (int p = tid; p < NPTS; p += 512) {
            float4* d = (float4*)&pts4[p * 4];
            *d = make_float4(src[p * 3 + 0], src[p * 3 + 1], src[p * 3 + 2], 0.f);
        }
        if (tid < QPB) flagq[tid] = 0;
        if (tid == 0)  ticket = 0;
    }
    __syncthreads();

    const float* xb = x + (size_t)b * NPTS * NF;

    if (w < NSEL) {
        // ================= SELECT role (pure VALU/LDS, no global loads) =================
        const uint64_t lmlt = (1ull << lane) - 1ull;
        uint32_t db[32];

        auto countLE = [&](uint32_t t) -> uint32_t {
            uint32_t c = 0;
            #pragma unroll
            for (int j = 0; j < 32; ++j)
                c += (uint32_t)__builtin_popcountll(__ballot(db[j] <= t));
            return c;
        };

        auto distTo = [&](int qi) {
            const float4 qp = *(const float4*)&pts4[qi * 4];
            #pragma unroll
            for (int j = 0; j < 32; ++j) {
                const int n = lane + (j << 6);
                const float4 pp = *(const float4*)&pts4[n * 4];
                const float dx = qp.x - pp.x;
                const float dy = qp.y - pp.y;
                const float dz = qp.z - pp.z;
                db[j] = __float_as_uint(dx * dx + dy * dy + dz * dz);
            }
        };

        // compact <=64 candidates to LDS keys, 15-round merge-select + min-merge:
        // lanes 0..31 end with the 32 smallest (d2,idx) keys (unordered; maxpool
        // is order-invariant; set matches ref tie order). Requires 32<=cthr<=64.
        // (merge-select validated by passing runs R3/R4.)
        auto compactSelect = [&](uint32_t thr, uint32_t cthr) -> int {
            uint32_t base = 0;
            #pragma unroll
            for (int j = 0; j < 32; ++j) {
                const bool     p = db[j] <= thr;
                const uint64_t m = __ballot(p);
                if (p) {
                    const int slot = (int)base + (int)__popcll(m & lmlt);
                    ckey[w][slot] = (((uint64_t)db[j]) << 11) | (uint64_t)(lane + (j << 6));
                }
                base += (uint32_t)__builtin_popcountll(m);
            }
            uint64_t key = (lane < (int)cthr) ? ckey[w][lane] : ~0ull;
            #pragma unroll
            for (int k = 2; k <= 32; k <<= 1) {
                #pragma unroll
                for (int j = k >> 1; j > 0; j >>= 1) {
                    const uint64_t other = __shfl_xor((unsigned long long)key, j);
                    const bool takeMin = (((lane & j) == 0) == ((lane & k) == 0));
                    key = ((key < other) == takeMin) ? key : other;
                }
            }
            {
                const uint64_t other = __shfl_xor((unsigned long long)key, 32);
                const uint64_t mn = key < other ? key : other;
                const uint64_t mx = key < other ? other : key;
                key = ((lane & 32) == 0) ? mn : mx;
            }
            return (int)(key & 0x7FFull);
        };

        // exact-tie fallback: all <T, then ==T ascending index (ref tie order)
        auto tieFallback = [&](uint32_t T, int cnt_lt) -> int {
            int base_lt = 0, base_eq = 0;
            #pragma unroll
            for (int j = 0; j < 32; ++j) {
                const bool lt = db[j] < T;
                const bool eq = db[j] == T;
                const uint64_t mlt = __ballot(lt);
                const uint64_t meq = __ballot(eq);
                int slot = -1;
                if (lt)      slot = base_lt + (int)__popcll(mlt & lmlt);
                else if (eq) slot = cnt_lt + base_eq + (int)__popcll(meq & lmlt);
                if (slot >= 0 && slot < KNN) tiebuf[w][slot] = lane + (j << 6);
                base_lt += (int)__popcll(mlt);
                base_eq += (int)__popcll(meq);
            }
            return tiebuf[w][lane & (KNN - 1)];
        };

        auto selectFull = [&]() -> int {
            uint32_t lmin = db[0];
            #pragma unroll
            for (int j = 1; j < 32; ++j) lmin = min(lmin, db[j]);
            uint32_t sm = lmin;
            #pragma unroll
            for (int k = 2; k <= 64; k <<= 1) {
                #pragma unroll
                for (int j = k >> 1; j > 0; j >>= 1) {
                    const uint32_t o  = (uint32_t)__shfl_xor((int)sm, j);
                    const uint32_t mn = min(sm, o);
                    const uint32_t mx = max(sm, o);
                    sm = (((lane & j) == 0) == ((lane & k) == 0)) ? mn : mx;
                }
            }
            const uint32_t probe = (uint32_t)__builtin_amdgcn_readlane((int)sm, 31);
            const uint32_t hi0   = (uint32_t)__builtin_amdgcn_readlane((int)sm, 63);

            const uint32_t c1 = countLE(probe);          // >= 32 guaranteed
            if (c1 <= 64u) return compactSelect(probe, c1);
            const uint32_t cs = countLE(hi0);            // >= 64 guaranteed
            if (cs <= 64u) return compactSelect(hi0, cs);
            if (probe == 0u) return tieFallback(0u, 0);  // >=65 zero-distance dups
            uint32_t lo = 0u, hi = probe;                // c(lo)<32 (self), c(hi)>64
            while (hi - lo > 1u) {
                const uint32_t mid = lo + ((hi - lo) >> 1);
                const uint32_t c   = countLE(mid);
                if (c >= KNN && c <= 64u) return compactSelect(mid, c);
                if (c > 64u) hi = mid; else lo = mid;
            }
            return tieFallback(hi, (int)countLE(lo));    // count(<=lo) == count(<hi)
        };

        for (int t = 0; t < QPB / NSEL; ++t) {
            const int q = t * NSEL + w;     // ready order == ticket order (0,1,2,...)
            distTo(iBase + q);
            const int selv = selectFull();
            if (lane < KNN) selq[q][lane] = selv;
            __threadfence_block();          // drain ds_writes before release
            if (lane == 0)
                __hip_atomic_store(&flagq[q], 1, __ATOMIC_RELEASE,
                                   __HIP_MEMORY_SCOPE_WORKGROUP);
        }
    } else {
        // ================= GATHER role (pure VMEM + fmax, no db[]) =================
        for (;;) {
            int t;
            if (lane == 0) t = atomicAdd(&ticket, 1);   // LDS atomic, one per wave
            t = __shfl(t, 0);
            if (t >= QPB) break;

            while (__hip_atomic_load(&flagq[t], __ATOMIC_ACQUIRE,
                                     __HIP_MEMORY_SCOPE_WORKGROUP) == 0)
                __builtin_amdgcn_s_sleep(2);

            const int selv = selq[t][lane & (KNN - 1)];   // lane k holds index k

            float4 a0 = make_float4(-INFINITY, -INFINITY, -INFINITY, -INFINITY);
            float4 a1 = a0;
            #pragma unroll 4   // R1's proven no-spill gather shape
            for (int jj = 0; jj < 32; jj += 2) {
                const int n0 = __builtin_amdgcn_readlane(selv, jj)     & (NPTS - 1);
                const int n1 = __builtin_amdgcn_readlane(selv, jj + 1) & (NPTS - 1);
                const float4* r0 = (const float4*)(xb + (size_t)n0 * NF);
                const float4* r1 = (const float4*)(xb + (size_t)n1 * NF);
                const float4 v00 = r0[lane];
                const float4 v01 = r0[lane + 64];
                const float4 v10 = r1[lane];
                const float4 v11 = r1[lane + 64];
                a0.x = fmaxf(fmaxf(a0.x, v00.x), v10.x);
                a0.y = fmaxf(fmaxf(a0.y, v00.y), v10.y);
                a0.z = fmaxf(fmaxf(a0.z, v00.z), v10.z);
                a0.w = fmaxf(fmaxf(a0.w, v00.w), v10.w);
                a1.x = fmaxf(fmaxf(a1.x, v01.x), v11.x);
                a1.y = fmaxf(fmaxf(a1.y, v01.y), v11.y);
                a1.z = fmaxf(fmaxf(a1.z, v01.z), v11.z);
                a1.w = fmaxf(fmaxf(a1.w, v01.w), v11.w);
            }
            vfloat4* orow = (vfloat4*)(out + ((size_t)b * NPTS + iBase + t) * NF);
            __builtin_nontemporal_store(vfloat4{a0.x, a0.y, a0.z, a0.w}, &orow[lane]);
            __builtin_nontemporal_store(vfloat4{a1.x, a1.y, a1.z, a1.w}, &orow[lane + 64]);
        }
    }
}

extern "C" void kernel_launch(void* const* d_in, const int* in_sizes, int n_in,
                              void* d_out, int out_size, void* d_ws, size_t ws_size,
                              hipStream_t stream) {
    const float* x      = (const float*)d_in[0];   // [8, 2048, 512] f32
    const float* points = (const float*)d_in[1];   // [8, 2048, 3]   f32
    float* out          = (float*)d_out;           // [8, 2048, 512] f32

    pointnetpp_knn_maxpool<<<dim3(BATCHES * (NPTS / QPB)),
                             dim3(512), 0, stream>>>(x, points, out);
}

// Round 6
// 300.340 us; speedup vs baseline: 1.2215x; 1.1986x over previous
//
#include <hip/hip_runtime.h>
#include <cstdint>

#define BATCHES 8
#define NPTS 2048
#define NF 512
#define KNN 32
#define QPB 16     // queries per block; wave 0 produces, all 8 waves consume

// R6: producer/consumer waves + STATELESS select (recompute instead of db[32]).
// R3/R4/R5 post-mortem chain: db[32] kept live in any structure other than the
// R0 straight-line form => allocator abandons AGPR-shelving and scratch-spills
// 8 KB/query (R5: WRITE 171 MB, FETCH 218 MB, producers serialized at HBM
// latency, 300us). Fix: select recomputes distances per pass via one
// __forceinline__ fmaf-chain helper (bit-identical across passes), so select
// state is ~6 scalars. Wave 0 selects 16 queries -> selq+flag; waves 0-7 pop
// tickets and gather (wave 0 joins after producing). grid = 8*128 = 1024
// blocks = 4/CU resident (LDS ~35.5 KB); batch = blockIdx & 7 (XCD L2 affinity,
// x[b] = 4 MB fits one XCD L2). Gather floor: 1 GiB / 34.5 TB/s ~= 30 us.
// Spill tripwires: WRITE_SIZE == 32768 KB exactly, FETCH ~= 27.5 MB.

typedef float vfloat4 __attribute__((ext_vector_type(4)));  // native vec for nt-store

// single definition => bit-identical distance on every pass (correctness invariant)
__device__ __forceinline__ uint32_t d2u(const float4 qp, const float* pts4, const int n) {
    const float4 pp = *(const float4*)&pts4[n * 4];
    const float dx = qp.x - pp.x;
    const float dy = qp.y - pp.y;
    const float dz = qp.z - pp.z;
    return __float_as_uint(fmaf(dz, dz, fmaf(dy, dy, dx * dx)));
}

__global__ __launch_bounds__(512, 4)
void pointnetpp_knn_maxpool(const float* __restrict__ x,
                            const float* __restrict__ points,
                            float* __restrict__ out) {
    __shared__ __align__(16) float    pts4[NPTS * 4];   // [N][4]: one b128/candidate
    __shared__ __align__(16) uint64_t ckey[64];         // select scratch (wave 0 only)
    __shared__ __align__(16) int      tiebuf[KNN];      // tie-fallback emit (wave 0)
    __shared__ __align__(16) int      selq[QPB][KNN];   // producer -> consumers
    __shared__ int flagq[QPB];                          // release flags
    __shared__ int ticket;                              // gather work counter

    const int tid  = threadIdx.x;
    const int lane = tid & 63;
    const int w    = tid >> 6;

    const int b     = blockIdx.x & 7;
    const int chunk = blockIdx.x >> 3;
    const int iBase = chunk * QPB;

    // ---- stage points[b] into LDS as [N][4] (pad .w); init flags/ticket ----
    {
        const float* src = points + (size_t)b * NPTS * 3;
        for (int p = tid; p < NPTS; p += 512) {
            float4* d = (float4*)&pts4[p * 4];
            *d = make_float4(src[p * 3 + 0], src[p * 3 + 1], src[p * 3 + 2], 0.f);
        }
        if (tid < QPB) flagq[tid] = 0;
        if (tid == 0)  ticket = 0;
    }
    __syncthreads();

    const float* xb = x + (size_t)b * NPTS * NF;

    if (w == 0) {
        // ============ PRODUCER: stateless select, 16 queries in order ============
        const uint64_t lmlt = (1ull << lane) - 1ull;

        auto countLE = [&](const float4 qp, uint32_t t) -> uint32_t {
            uint32_t c = 0;
            #pragma unroll
            for (int j = 0; j < 32; ++j)
                c += (uint32_t)__builtin_popcountll(
                        __ballot(d2u(qp, pts4, lane + (j << 6)) <= t));
            return c;
        };

        // recompute + compact <=64 keys to LDS, then top-32 merge-select
        // (15 bitonic rounds k=2..32 + min-merge; maxpool is order-invariant,
        // set matches ref tie order via (d2,idx) keys). Requires 32<=cthr<=64.
        auto compactSelect = [&](const float4 qp, uint32_t thr, uint32_t cthr) -> int {
            uint32_t base = 0;
            #pragma unroll
            for (int j = 0; j < 32; ++j) {
                const uint32_t d = d2u(qp, pts4, lane + (j << 6));
                const bool     p = d <= thr;
                const uint64_t m = __ballot(p);
                if (p) {
                    const int slot = (int)base + (int)__popcll(m & lmlt);
                    ckey[slot] = (((uint64_t)d) << 11) | (uint64_t)(lane + (j << 6));
                }
                base += (uint32_t)__builtin_popcountll(m);
            }
            uint64_t key = (lane < (int)cthr) ? ckey[lane] : ~0ull;
            #pragma unroll
            for (int k = 2; k <= 32; k <<= 1) {
                #pragma unroll
                for (int j = k >> 1; j > 0; j >>= 1) {
                    const uint64_t other = __shfl_xor((unsigned long long)key, j);
                    const bool takeMin = (((lane & j) == 0) == ((lane & k) == 0));
                    key = ((key < other) == takeMin) ? key : other;
                }
            }
            {
                const uint64_t other = __shfl_xor((unsigned long long)key, 32);
                const uint64_t mn = key < other ? key : other;
                const uint64_t mx = key < other ? other : key;
                key = ((lane & 32) == 0) ? mn : mx;
            }
            return (int)(key & 0x7FFull);
        };

        // exact-tie fallback: all <T, then ==T ascending index (ref tie order)
        auto tieFallback = [&](const float4 qp, uint32_t T, int cnt_lt) -> int {
            int base_lt = 0, base_eq = 0;
            #pragma unroll
            for (int j = 0; j < 32; ++j) {
                const uint32_t d = d2u(qp, pts4, lane + (j << 6));
                const bool lt = d < T;
                const bool eq = d == T;
                const uint64_t mlt = __ballot(lt);
                const uint64_t meq = __ballot(eq);
                int slot = -1;
                if (lt)      slot = base_lt + (int)__popcll(mlt & lmlt);
                else if (eq) slot = cnt_lt + base_eq + (int)__popcll(meq & lmlt);
                if (slot >= 0 && slot < KNN) tiebuf[slot] = lane + (j << 6);
                base_lt += (int)__popcll(mlt);
                base_eq += (int)__popcll(meq);
            }
            return tiebuf[lane & (KNN - 1)];
        };

        auto selectFull = [&](const float4 qp) -> int {
            // pass 1: per-lane min (1 reg) + 21-round bitonic sort of 64 minima
            uint32_t lmin = 0xFFFFFFFFu;
            #pragma unroll
            for (int j = 0; j < 32; ++j)
                lmin = min(lmin, d2u(qp, pts4, lane + (j << 6)));
            uint32_t sm = lmin;
            #pragma unroll
            for (int k = 2; k <= 64; k <<= 1) {
                #pragma unroll
                for (int j = k >> 1; j > 0; j >>= 1) {
                    const uint32_t o  = (uint32_t)__shfl_xor((int)sm, j);
                    const uint32_t mn = min(sm, o);
                    const uint32_t mx = max(sm, o);
                    sm = (((lane & j) == 0) == ((lane & k) == 0)) ? mn : mx;
                }
            }
            const uint32_t probe = (uint32_t)__builtin_amdgcn_readlane((int)sm, 31);
            const uint32_t hi0   = (uint32_t)__builtin_amdgcn_readlane((int)sm, 63);

            // pass 2: count; probe = 32nd-smallest lane-min -> countLE >= 32
            const uint32_t c1 = countLE(qp, probe);
            if (c1 <= 64u) return compactSelect(qp, probe, c1);
            const uint32_t cs = countLE(qp, hi0);        // >= 64 guaranteed
            if (cs <= 64u) return compactSelect(qp, hi0, cs);
            if (probe == 0u) return tieFallback(qp, 0u, 0);  // >=65 coincident pts
            uint32_t lo = 0u, hi = probe;                // c(lo)<32 (self), c(hi)>64
            while (hi - lo > 1u) {
                const uint32_t mid = lo + ((hi - lo) >> 1);
                const uint32_t c   = countLE(qp, mid);
                if (c >= KNN && c <= 64u) return compactSelect(qp, mid, c);
                if (c > 64u) hi = mid; else lo = mid;
            }
            return tieFallback(qp, hi, (int)countLE(qp, lo));  // c(<=lo)==c(<hi)
        };

        for (int q = 0; q < QPB; ++q) {   // ready order == ticket order
            const float4 qp = *(const float4*)&pts4[(iBase + q) * 4];
            const int selv = selectFull(qp);
            if (lane < KNN) selq[q][lane] = selv;
            __threadfence_block();        // drain ds_writes before release
            if (lane == 0)
                __hip_atomic_store(&flagq[q], 1, __ATOMIC_RELEASE,
                                   __HIP_MEMORY_SCOPE_WORKGROUP);
        }
    }

    // ============ CONSUMER: all 8 waves (wave 0 joins after producing) ============
    for (;;) {
        int t;
        if (lane == 0) t = atomicAdd(&ticket, 1);   // LDS atomic, one per wave
        t = __shfl(t, 0);
        if (t >= QPB) break;

        while (__hip_atomic_load(&flagq[t], __ATOMIC_ACQUIRE,
                                 __HIP_MEMORY_SCOPE_WORKGROUP) == 0)
            __builtin_amdgcn_s_sleep(4);

        const int selv = selq[t][lane & (KNN - 1)];   // lane k holds index k

        float4 a0 = make_float4(-INFINITY, -INFINITY, -INFINITY, -INFINITY);
        float4 a1 = a0;
        #pragma unroll 4   // R1's proven no-spill gather shape
        for (int jj = 0; jj < 32; jj += 2) {
            const int n0 = __builtin_amdgcn_readlane(selv, jj)     & (NPTS - 1);
            const int n1 = __builtin_amdgcn_readlane(selv, jj + 1) & (NPTS - 1);
            const float4* r0 = (const float4*)(xb + (size_t)n0 * NF);
            const float4* r1 = (const float4*)(xb + (size_t)n1 * NF);
            const float4 v00 = r0[lane];
            const float4 v01 = r0[lane + 64];
            const float4 v10 = r1[lane];
            const float4 v11 = r1[lane + 64];
            a0.x = fmaxf(fmaxf(a0.x, v00.x), v10.x);
            a0.y = fmaxf(fmaxf(a0.y, v00.y), v10.y);
            a0.z = fmaxf(fmaxf(a0.z, v00.z), v10.z);
            a0.w = fmaxf(fmaxf(a0.w, v00.w), v10.w);
            a1.x = fmaxf(fmaxf(a1.x, v01.x), v11.x);
            a1.y = fmaxf(fmaxf(a1.y, v01.y), v11.y);
            a1.z = fmaxf(fmaxf(a1.z, v01.z), v11.z);
            a1.w = fmaxf(fmaxf(a1.w, v01.w), v11.w);
        }
        vfloat4* orow = (vfloat4*)(out + ((size_t)b * NPTS + iBase + t) * NF);
        __builtin_nontemporal_store(vfloat4{a0.x, a0.y, a0.z, a0.w}, &orow[lane]);
        __builtin_nontemporal_store(vfloat4{a1.x, a1.y, a1.z, a1.w}, &orow[lane + 64]);
    }
}

extern "C" void kernel_launch(void* const* d_in, const int* in_sizes, int n_in,
                              void* d_out, int out_size, void* d_ws, size_t ws_size,
                              hipStream_t stream) {
    const float* x      = (const float*)d_in[0];   // [8, 2048, 512] f32
    const float* points = (const float*)d_in[1];   // [8, 2048, 3]   f32
    float* out          = (float*)d_out;           // [8, 2048, 512] f32

    pointnetpp_knn_maxpool<<<dim3(BATCHES * (NPTS / QPB)),
                             dim3(512), 0, stream>>>(x, points, out);
}